// Round 1
// baseline (4207.726 us; speedup 1.0000x reference)
//
#include <hip/hip_runtime.h>

#define T_  4
#define C_  256
#define H_  256
#define W_  256
#define S_  9
#define HW_ (H_*W_)
#define NH  4
#define HD  64
#define KK  25
#define NPIX_ (T_*HW_)   // 262144 pixels total

typedef unsigned short ushort_t;
typedef __bf16 bf16x8 __attribute__((ext_vector_type(8)));
typedef float  f32x4  __attribute__((ext_vector_type(4)));

__device__ __forceinline__ unsigned short f2bf(float f) {
    unsigned u = __builtin_bit_cast(unsigned, f);
    u += 0x7fffu + ((u >> 16) & 1u);          // RNE
    return (unsigned short)(u >> 16);
}
__device__ __forceinline__ float bflo(unsigned u) {
    return __builtin_bit_cast(float, u << 16);
}
__device__ __forceinline__ float bfhi(unsigned u) {
    return __builtin_bit_cast(float, u & 0xffff0000u);
}
__device__ __forceinline__ float bfs(ushort_t u) {       // single bf16 -> f32
    return __builtin_bit_cast(float, ((unsigned)u) << 16);
}
__device__ __forceinline__ void gload16(const ushort_t* g, ushort_t* l) {
    __builtin_amdgcn_global_load_lds(
        (const __attribute__((address_space(1))) void*)g,
        (__attribute__((address_space(3))) void*)l, 16, 0, 0);
}

// ---------------------------------------------------------------------------
// Weight prep: Wt[1024][256] bf16; rows 0..255 = Wq^T * 0.125, 256.. = Wk^T,
// 512.. = Wv^T, 768.. = Wp^T.   Wt[r][ci] = W[ci][co], co = r & 255.
// ---------------------------------------------------------------------------
__global__ __launch_bounds__(256)
void prep_w(const float* __restrict__ Wq, const float* __restrict__ Wk,
            const float* __restrict__ Wv, const float* __restrict__ Wp,
            ushort_t* __restrict__ Wt)
{
    int r = blockIdx.x;            // 0..1023
    int m = r >> 8, co = r & 255;
    int ci = threadIdx.x;
    const float* W = (m == 0) ? Wq : ((m == 1) ? Wk : ((m == 2) ? Wv : Wp));
    float s = (m == 0) ? 0.125f : 1.0f;
    Wt[(size_t)r * 256 + ci] = f2bf(W[(size_t)ci * 256 + co] * s);
}

// ---------------------------------------------------------------------------
// X cast+transpose: [T,C,HW] fp32 -> [T,HW,C] bf16.  64x64 LDS tiles.
// ---------------------------------------------------------------------------
__global__ __launch_bounds__(256)
void cast_x(const float* __restrict__ X, ushort_t* __restrict__ Xt)
{
    int hw0 = blockIdx.x * 64, c0 = blockIdx.y * 64, t = blockIdx.z;
    __shared__ ushort_t lds[64][68];
    int tid = threadIdx.x;
    const float* xb = X + ((size_t)t * C_ + c0) * HW_ + hw0;
#pragma unroll
    for (int i = 0; i < 4; i++) {
        int idx = tid + i * 256;
        int c = idx >> 4, col4 = idx & 15;
        float4 v = *(const float4*)(xb + (size_t)c * HW_ + col4 * 4);
        ushort4 u = make_ushort4(f2bf(v.x), f2bf(v.y), f2bf(v.z), f2bf(v.w));
        *(ushort4*)&lds[c][col4 * 4] = u;
    }
    __syncthreads();
    ushort_t* ob = Xt + ((size_t)t * HW_ + hw0) * C_ + c0;
#pragma unroll
    for (int i = 0; i < 4; i++) {
        int idx = tid + i * 256;
        int hw = idx >> 4, c4 = idx & 15;
        ushort4 u = make_ushort4(lds[c4 * 4 + 0][hw], lds[c4 * 4 + 1][hw],
                                 lds[c4 * 4 + 2][hw], lds[c4 * 4 + 3][hw]);
        *(ushort4*)(ob + (size_t)hw * C_ + c4 * 4) = u;
    }
}

// ---------------------------------------------------------------------------
// MFMA GEMM: C[n][co] = sum_ci A[n][ci] * Bt[co][ci], A pixel-major bf16,
// Bt = pre-transposed weights bf16.  Tile 128x128, BK=32, 4 waves @ 64x64.
// mode 0: bf16 out CHANNEL-MAJOR [co][NPIX], split by co into o0/o1/o2.
// mode 1: fp32 out channel-major [T,C,H,W] (float4 along n).
// ---------------------------------------------------------------------------
__global__ __launch_bounds__(256)
void gemm_mfma(const ushort_t* __restrict__ A, const ushort_t* __restrict__ Bt,
               ushort_t* __restrict__ o0, ushort_t* __restrict__ o1,
               ushort_t* __restrict__ o2, float* __restrict__ of, int mode)
{
    __shared__ ushort_t As[128 * 32];
    __shared__ ushort_t Bs[128 * 32];
    const int tid = threadIdx.x, ln = tid & 63, wv = tid >> 6;
    const int n0  = blockIdx.x * 128;
    const int co0 = blockIdx.y * 128;
    const int m_off = (wv & 1) * 64, n_off = (wv >> 1) * 64;

    f32x4 acc[4][4];
#pragma unroll
    for (int i = 0; i < 4; i++)
#pragma unroll
        for (int j = 0; j < 4; j++) acc[i][j] = (f32x4){0.f, 0.f, 0.f, 0.f};

    const int srow = ln >> 2, scol = (ln & 3) * 8;
    const ushort_t* gA = A  + (size_t)(n0  + srow) * 256 + scol;
    const ushort_t* gB = Bt + (size_t)(co0 + srow) * 256 + scol;
    const int quad = ln >> 4, lm = ln & 15;

#pragma unroll
    for (int k0 = 0; k0 < 256; k0 += 32) {
#pragma unroll
        for (int c = 0; c < 2; c++) {
            int rr = wv * 32 + c * 16;
            gload16(gA + (size_t)rr * 256 + k0, As + rr * 32);
            gload16(gB + (size_t)rr * 256 + k0, Bs + rr * 32);
        }
        __syncthreads();
        bf16x8 af[4], bfr[4];
#pragma unroll
        for (int mt = 0; mt < 4; mt++)
            af[mt] = *(const bf16x8*)&As[(m_off + mt * 16 + lm) * 32 + quad * 8];
#pragma unroll
        for (int nt = 0; nt < 4; nt++)
            bfr[nt] = *(const bf16x8*)&Bs[(n_off + nt * 16 + lm) * 32 + quad * 8];
#pragma unroll
        for (int mt = 0; mt < 4; mt++)
#pragma unroll
            for (int nt = 0; nt < 4; nt++)
                acc[mt][nt] = __builtin_amdgcn_mfma_f32_16x16x32_bf16(
                    af[mt], bfr[nt], acc[mt][nt], 0, 0, 0);
        __syncthreads();
    }

    if (mode == 0) {
        // channel-major store: op[co][n], 4 consecutive pixels per lane (8 B).
#pragma unroll
        for (int mt = 0; mt < 4; mt++) {
            int nb = n0 + m_off + mt * 16 + quad * 4;
#pragma unroll
            for (int nt = 0; nt < 4; nt++) {
                int co = co0 + n_off + nt * 16 + lm;
                int arr = co >> 8, ci = co & 255;
                ushort_t* op = (arr == 0) ? o0 : ((arr == 1) ? o1 : o2);
                ushort4 u = make_ushort4(f2bf(acc[mt][nt][0]), f2bf(acc[mt][nt][1]),
                                         f2bf(acc[mt][nt][2]), f2bf(acc[mt][nt][3]));
                *(ushort4*)(op + (size_t)ci * NPIX_ + nb) = u;
            }
        }
    } else {
#pragma unroll
        for (int mt = 0; mt < 4; mt++) {
            int nb = n0 + m_off + mt * 16 + quad * 4;
            int tt = nb >> 16, hwb = nb & (HW_ - 1);
            float* ob = of + (size_t)tt * (C_ * (size_t)HW_) + hwb;
#pragma unroll
            for (int nt = 0; nt < 4; nt++) {
                int cg = co0 + n_off + nt * 16 + lm;
                float4 val = make_float4(acc[mt][nt][0], acc[mt][nt][1],
                                         acc[mt][nt][2], acc[mt][nt][3]);
                *(float4*)(ob + (size_t)cg * HW_) = val;
            }
        }
    }
}

// ---------------------------------------------------------------------------
// Attention v3: channel-major bf16 q/k/v [co][NPIX].  Block = 64-pixel strip,
// wave = head, lane = pixel.  All k/v loads are coalesced (2 B/lane,
// contiguous across lanes); neighbor indexing via precomputed per-lane byte
// offsets pb[e] against a wave-uniform (SGPR) channel-row base.
// Logits live in registers (fully unrolled e-loops); LDS only holds the
// superpixel sim weights.  Output ao stays pixel-major for the proj GEMM.
// ---------------------------------------------------------------------------
__global__ __launch_bounds__(256)
void attn3(const ushort_t* __restrict__ q, const ushort_t* __restrict__ k,
           const ushort_t* __restrict__ v, const float* __restrict__ sims,
           ushort_t* __restrict__ ao)
{
    const int w0 = blockIdx.x * 64, h = blockIdx.y, t = blockIdx.z;
    const int tid = threadIdx.x, ln = tid & 63;
    const int head = __builtin_amdgcn_readfirstlane(tid >> 6);
    const int w = w0 + ln, hw = h * W_ + w;

    __shared__ float sw[KK][64];

    // superpixel similarity weights, split across waves (coalesced fp32 loads)
    {
        const float* sp = sims + (size_t)t * S_ * HW_;
        float s0[S_];
#pragma unroll
        for (int s = 0; s < S_; s++) s0[s] = sp[s * HW_ + hw];
#pragma unroll 1
        for (int e = head; e < KK; e += NH) {
            int di = e / 5 - 2, dj = e % 5 - 2;
            int h2 = min(max(h + di, 0), H_ - 1);
            int w2 = min(max(w + dj, 0), W_ - 1);
            int o = h2 * W_ + w2;
            float a = 0.f;
#pragma unroll
            for (int s = 0; s < S_; s++) a += s0[s] * sp[s * HW_ + o];
            sw[e][ln] = a;
        }
    }

    // per-lane neighbor byte offsets within one image plane (bf16 = 2 B)
    int pb[KK];
#pragma unroll
    for (int e = 0; e < KK; e++) {
        const int di = e / 5 - 2, dj = e % 5 - 2;
        int h2 = min(max(h + di, 0), H_ - 1);
        int w2 = min(max(w + dj, 0), W_ - 1);
        pb[e] = (h2 * W_ + w2) * 2;
    }

    const size_t cstride = (size_t)NPIX_ * 2;   // bytes per channel row
    const char* kt = (const char*)k + (size_t)(head * HD) * cstride + (size_t)t * HW_ * 2;
    const char* qt = (const char*)q + (size_t)(head * HD) * cstride
                                    + ((size_t)t * HW_ + hw) * 2;

    // ---- QK logits, accumulated over channels in registers --------------
    float lg[KK];
#pragma unroll
    for (int e = 0; e < KK; e++) lg[e] = 0.f;

#pragma unroll 4
    for (int c = 0; c < HD; c++) {
        float qf = bfs(*(const ushort_t*)(qt + (size_t)c * cstride));
        const char* kc = kt + (size_t)c * cstride;
#pragma unroll
        for (int e = 0; e < KK; e++)
            lg[e] += qf * bfs(*(const ushort_t*)(kc + pb[e]));
    }

    __syncthreads();   // sw ready

    // ---- exp-shift, sim reweight; defer the 1/sum into the output scale -
    float mx = lg[0];
#pragma unroll
    for (int e = 1; e < KK; e++) mx = fmaxf(mx, lg[e]);
    float sum = 0.f;
#pragma unroll
    for (int e = 0; e < KK; e++) {
        float p = __expf(lg[e] - mx) * sw[e][ln];
        sum += p;
        lg[e] = p;
    }
    const float inv = 1.0f / (1e-10f + sum);

    // ---- PV, 16 channels per chunk (oa in regs, compile-time indices) ---
    const char* vt = (const char*)v + (size_t)(head * HD) * cstride + (size_t)t * HW_ * 2;
    ushort_t* ab = ao + ((size_t)t * HW_ + hw) * 256 + head * HD;

#pragma unroll 1
    for (int cc = 0; cc < 4; cc++) {
        const char* vc = vt + (size_t)(cc * 16) * cstride;
        float oa[16];
#pragma unroll
        for (int i = 0; i < 16; i++) oa[i] = 0.f;
#pragma unroll
        for (int e = 0; e < KK; e++) {
            float wgt = lg[e];
#pragma unroll
            for (int i = 0; i < 16; i++)
                oa[i] += wgt * bfs(*(const ushort_t*)(vc + (size_t)i * cstride + pb[e]));
        }
        unsigned pk[8];
#pragma unroll
        for (int j = 0; j < 8; j++)
            pk[j] = (unsigned)f2bf(oa[2 * j] * inv)
                  | ((unsigned)f2bf(oa[2 * j + 1] * inv) << 16);
        uint4* stp = (uint4*)(ab + cc * 16);
        stp[0] = make_uint4(pk[0], pk[1], pk[2], pk[3]);
        stp[1] = make_uint4(pk[4], pk[5], pk[6], pk[7]);
    }
}

// ---------------------------------------------------------------------------
extern "C" void kernel_launch(void* const* d_in, const int* in_sizes, int n_in,
                              void* d_out, int out_size, void* d_ws, size_t ws_size,
                              hipStream_t stream)
{
    const float* x    = (const float*)d_in[0];
    const float* sims = (const float*)d_in[1];
    // d_in[2] = flows: zeros (wt = 0) -> unused
    const float* Wq   = (const float*)d_in[3];
    const float* Wk   = (const float*)d_in[4];
    const float* Wv   = (const float*)d_in[5];
    const float* Wp   = (const float*)d_in[6];
    float* out = (float*)d_out;

    const size_t NCH = (size_t)NPIX_ * 256;      // elements per tensor

    ushort_t* Wt = (ushort_t*)d_ws;                       // 512 KB
    ushort_t* Xt = (ushort_t*)((char*)d_ws + (1 << 20));  // 134 MB each below
    ushort_t* qq = Xt + NCH;
    ushort_t* kk = qq + NCH;
    ushort_t* vv = kk + NCH;
    ushort_t* ao = vv + NCH;

    prep_w<<<1024, 256, 0, stream>>>(Wq, Wk, Wv, Wp, Wt);
    cast_x<<<dim3(HW_ / 64, C_ / 64, T_), 256, 0, stream>>>(x, Xt);

    // QKV: N = 768 (q|k|v stacked in Wt rows 0..767) -> channel-major bf16
    gemm_mfma<<<dim3(NPIX_ / 128, 6), 256, 0, stream>>>(Xt, Wt, qq, kk, vv, nullptr, 0);

    attn3<<<dim3(W_ / 64, H_, T_), 256, 0, stream>>>(qq, kk, vv, sims, ao);

    // output projection: Wp^T at rows 768.., fp32 channel-major out
    gemm_mfma<<<dim3(NPIX_ / 128, 2), 256, 0, stream>>>(ao, Wt + 768 * 256,
                                                        nullptr, nullptr, nullptr, out, 1);
}

// Round 3
// 2351.145 us; speedup vs baseline: 1.7896x; 1.7896x over previous
//
#include <hip/hip_runtime.h>

#define T_  4
#define C_  256
#define H_  256
#define W_  256
#define S_  9
#define HW_ (H_*W_)
#define NH  4
#define HD  64
#define KK  25
#define NPIX_ (T_*HW_)

typedef unsigned short ushort_t;
typedef __bf16 bf16x8 __attribute__((ext_vector_type(8)));
typedef float  f32x4  __attribute__((ext_vector_type(4)));

__device__ __forceinline__ unsigned short f2bf(float f) {
    unsigned u = __builtin_bit_cast(unsigned, f);
    u += 0x7fffu + ((u >> 16) & 1u);          // RNE
    return (unsigned short)(u >> 16);
}
__device__ __forceinline__ float bflo(unsigned u) {
    return __builtin_bit_cast(float, u << 16);
}
__device__ __forceinline__ float bfhi(unsigned u) {
    return __builtin_bit_cast(float, u & 0xffff0000u);
}
__device__ __forceinline__ void gload16(const ushort_t* g, ushort_t* l) {
    __builtin_amdgcn_global_load_lds(
        (const __attribute__((address_space(1))) void*)g,
        (__attribute__((address_space(3))) void*)l, 16, 0, 0);
}

// ---------------------------------------------------------------------------
// Weight prep: Wt[1024][256] bf16; rows 0..255 = Wq^T * 0.125, 256.. = Wk^T,
// 512.. = Wv^T, 768.. = Wp^T.
// ---------------------------------------------------------------------------
__global__ __launch_bounds__(256)
void prep_w(const float* __restrict__ Wq, const float* __restrict__ Wk,
            const float* __restrict__ Wv, const float* __restrict__ Wp,
            ushort_t* __restrict__ Wt)
{
    int r = blockIdx.x;            // 0..1023
    int m = r >> 8, co = r & 255;
    int ci = threadIdx.x;
    const float* W = (m == 0) ? Wq : ((m == 1) ? Wk : ((m == 2) ? Wv : Wp));
    float s = (m == 0) ? 0.125f : 1.0f;
    Wt[(size_t)r * 256 + ci] = f2bf(W[(size_t)ci * 256 + co] * s);
}

// ---------------------------------------------------------------------------
// X cast+transpose: [T,C,HW] fp32 -> [T,HW,C] bf16.  64x64 LDS tiles.
// ---------------------------------------------------------------------------
__global__ __launch_bounds__(256)
void cast_x(const float* __restrict__ X, ushort_t* __restrict__ Xt)
{
    int hw0 = blockIdx.x * 64, c0 = blockIdx.y * 64, t = blockIdx.z;
    __shared__ ushort_t lds[64][68];
    int tid = threadIdx.x;
    const float* xb = X + ((size_t)t * C_ + c0) * HW_ + hw0;
#pragma unroll
    for (int i = 0; i < 4; i++) {
        int idx = tid + i * 256;
        int c = idx >> 4, col4 = idx & 15;
        float4 v = *(const float4*)(xb + (size_t)c * HW_ + col4 * 4);
        ushort4 u = make_ushort4(f2bf(v.x), f2bf(v.y), f2bf(v.z), f2bf(v.w));
        *(ushort4*)&lds[c][col4 * 4] = u;
    }
    __syncthreads();
    ushort_t* ob = Xt + ((size_t)t * HW_ + hw0) * C_ + c0;
#pragma unroll
    for (int i = 0; i < 4; i++) {
        int idx = tid + i * 256;
        int hw = idx >> 4, c4 = idx & 15;
        ushort4 u = make_ushort4(lds[c4 * 4 + 0][hw], lds[c4 * 4 + 1][hw],
                                 lds[c4 * 4 + 2][hw], lds[c4 * 4 + 3][hw]);
        *(ushort4*)(ob + (size_t)hw * C_ + c4 * 4) = u;
    }
}

// ---------------------------------------------------------------------------
// MFMA GEMM: C[n][co] = sum_ci A[n][ci] * Bt[co][ci].  Tile 128x128, BK=32.
// mode 0: bf16 out pixel-major [n][256], split by co into o0/o1/o2.
// mode 1: fp32 out channel-major [T,C,H,W] (float4 along n).
// ---------------------------------------------------------------------------
__global__ __launch_bounds__(256)
void gemm_mfma(const ushort_t* __restrict__ A, const ushort_t* __restrict__ Bt,
               ushort_t* __restrict__ o0, ushort_t* __restrict__ o1,
               ushort_t* __restrict__ o2, float* __restrict__ of, int mode)
{
    __shared__ ushort_t As[128 * 32];
    __shared__ ushort_t Bs[128 * 32];
    const int tid = threadIdx.x, ln = tid & 63, wv = tid >> 6;
    const int n0  = blockIdx.x * 128;
    const int co0 = blockIdx.y * 128;
    const int m_off = (wv & 1) * 64, n_off = (wv >> 1) * 64;

    f32x4 acc[4][4];
#pragma unroll
    for (int i = 0; i < 4; i++)
#pragma unroll
        for (int j = 0; j < 4; j++) acc[i][j] = (f32x4){0.f, 0.f, 0.f, 0.f};

    const int srow = ln >> 2, scol = (ln & 3) * 8;
    const ushort_t* gA = A  + (size_t)(n0  + srow) * 256 + scol;
    const ushort_t* gB = Bt + (size_t)(co0 + srow) * 256 + scol;
    const int quad = ln >> 4, lm = ln & 15;

#pragma unroll
    for (int k0 = 0; k0 < 256; k0 += 32) {
#pragma unroll
        for (int c = 0; c < 2; c++) {
            int rr = wv * 32 + c * 16;
            gload16(gA + (size_t)rr * 256 + k0, As + rr * 32);
            gload16(gB + (size_t)rr * 256 + k0, Bs + rr * 32);
        }
        __syncthreads();
        bf16x8 af[4], bfr[4];
#pragma unroll
        for (int mt = 0; mt < 4; mt++)
            af[mt] = *(const bf16x8*)&As[(m_off + mt * 16 + lm) * 32 + quad * 8];
#pragma unroll
        for (int nt = 0; nt < 4; nt++)
            bfr[nt] = *(const bf16x8*)&Bs[(n_off + nt * 16 + lm) * 32 + quad * 8];
#pragma unroll
        for (int mt = 0; mt < 4; mt++)
#pragma unroll
            for (int nt = 0; nt < 4; nt++)
                acc[mt][nt] = __builtin_amdgcn_mfma_f32_16x16x32_bf16(
                    af[mt], bfr[nt], acc[mt][nt], 0, 0, 0);
        __syncthreads();
    }

    if (mode == 0) {
        int arr = co0 >> 8;
        ushort_t* op = (arr == 0) ? o0 : ((arr == 1) ? o1 : o2);
        int cobase = (co0 & 255) + n_off;
#pragma unroll
        for (int mt = 0; mt < 4; mt++) {
            int nb = n0 + m_off + mt * 16 + quad * 4;
#pragma unroll
            for (int nt = 0; nt < 4; nt++) {
                int ci = cobase + nt * 16 + lm;
#pragma unroll
                for (int r = 0; r < 4; r++)
                    op[(size_t)(nb + r) * 256 + ci] = f2bf(acc[mt][nt][r]);
            }
        }
    } else {
#pragma unroll
        for (int mt = 0; mt < 4; mt++) {
            int nb = n0 + m_off + mt * 16 + quad * 4;
            int tt = nb >> 16, hwb = nb & (HW_ - 1);
            float* ob = of + (size_t)tt * (C_ * (size_t)HW_) + hwb;
#pragma unroll
            for (int nt = 0; nt < 4; nt++) {
                int cg = co0 + n_off + nt * 16 + lm;
                float4 val = make_float4(acc[mt][nt][0], acc[mt][nt][1],
                                         acc[mt][nt][2], acc[mt][nt][3]);
                *(float4*)(ob + (size_t)cg * HW_) = val;
            }
        }
    }
}

// ---------------------------------------------------------------------------
// Attention v5: LDS-tiled neighborhood attention (v4 + full 64-ch store).
// Block = (t, head, 16x16 pixel tile), 256 threads, 1 pixel/thread.
// Stage 20x20 halo of K (then V) in LDS, 144 B/pixel (pad 128->144 breaks
// the power-of-2 bank stride for the 64-lane ds_read_b128 neighbor reads).
// sims halo staged as [400][12] fp32 in the same buffer (phase before K).
// lg/sw/oa live in registers; all e-loops fully unrolled.
// ---------------------------------------------------------------------------
__global__ __launch_bounds__(256)
void attn_tile(const ushort_t* __restrict__ q, const ushort_t* __restrict__ k,
               const ushort_t* __restrict__ v, const float* __restrict__ sims,
               ushort_t* __restrict__ ao)
{
    const int tw = blockIdx.x * 16, th = blockIdx.y * 16;
    const int t = blockIdx.z >> 2, head = blockIdx.z & 3;
    const int tid = threadIdx.x;
    const int r = tid >> 4, c = tid & 15;

    __shared__ float4 smem4[3600];            // 57600 B
    ushort_t* kv = (ushort_t*)smem4;          // [400] x 72 ushorts (144 B)
    float*    sm = (float*)smem4;             // [400] x 12 floats

    const size_t tpix = (size_t)t * HW_;
    const int p0 = (r + 2) * 20 + (c + 2);    // own pixel in halo coords

    // ---- q into registers (fp32), issued early --------------------------
    const size_t qpix = tpix + (size_t)((th + r) << 8) + (tw + c);
    const ushort_t* qb = q + qpix * 256 + head * HD;
    float qf[HD];
#pragma unroll
    for (int i = 0; i < 8; i++) {
        uint4 x = *(const uint4*)(qb + i * 8);
        qf[i*8+0] = bflo(x.x); qf[i*8+1] = bfhi(x.x);
        qf[i*8+2] = bflo(x.y); qf[i*8+3] = bfhi(x.y);
        qf[i*8+4] = bflo(x.z); qf[i*8+5] = bfhi(x.z);
        qf[i*8+6] = bflo(x.w); qf[i*8+7] = bfhi(x.w);
    }

    // ---- phase 0: stage sims halo [400][12] -----------------------------
#pragma unroll 1
    for (int i = tid; i < 3600; i += 256) {
        int p = (i * 7282) >> 16;             // i / 9  (valid for i < 32768)
        int s = i - p * 9;
        int rr = (p * 13108) >> 18;           // p / 20 (valid for p < 819)
        int cc = p - rr * 20;
        int h2 = min(max(th + rr - 2, 0), H_ - 1);
        int w2 = min(max(tw + cc - 2, 0), W_ - 1);
        sm[p * 12 + s] = sims[(((size_t)t * S_ + s) << 16) + (h2 << 8) + w2];
    }
    __syncthreads();

    // ---- sw[25] = superpixel similarity weights (registers) -------------
    float sw_[KK];
    {
        const float* so = sm + p0 * 12;
        float4 A = *(const float4*)so;
        float4 B = *(const float4*)(so + 4);
        float  C = so[8];
        const float* sb = sm + (p0 - 42) * 12;
#pragma unroll
        for (int e = 0; e < KK; e++) {
            const int di = e / 5 - 2, dj = e % 5 - 2;
            const int doff = di * 20 + dj;
            const float* sn = sb + (doff + 42) * 12;
            float4 X = *(const float4*)sn;
            float4 Y = *(const float4*)(sn + 4);
            float  Z = sn[8];
            sw_[e] = A.x*X.x + A.y*X.y + A.z*X.z + A.w*X.w
                   + B.x*Y.x + B.y*Y.y + B.z*Y.z + B.w*Y.w + C*Z;
        }
    }
    __syncthreads();

    // ---- phase 1: stage K halo (400 px x 64 ch, 144 B/px) ---------------
    const ushort_t* kg = k + tpix * 256 + head * HD;
#pragma unroll 1
    for (int i = tid; i < 3200; i += 256) {
        int p = i >> 3, ch = i & 7;
        int rr = (p * 13108) >> 18;
        int cc = p - rr * 20;
        int h2 = min(max(th + rr - 2, 0), H_ - 1);
        int w2 = min(max(tw + cc - 2, 0), W_ - 1);
        const ushort_t* src = kg + (((size_t)((h2 << 8) + w2)) << 8) + ch * 8;
        *(uint4*)(kv + p * 72 + ch * 8) = *(const uint4*)src;
    }
    __syncthreads();

    // ---- QK logits (registers) ------------------------------------------
    float lg[KK];
    const ushort_t* kb = kv + (size_t)(p0 - 42) * 72;
#pragma unroll
    for (int e = 0; e < KK; e++) {
        const int di = e / 5 - 2, dj = e % 5 - 2;
        const int doff = di * 20 + dj;
        const ushort_t* kp = kb + (doff + 42) * 72;
        float a = 0.f;
#pragma unroll
        for (int j = 0; j < 8; j++) {
            uint4 kx = *(const uint4*)(kp + j * 8);
            a += qf[j*8+0] * bflo(kx.x); a += qf[j*8+1] * bfhi(kx.x);
            a += qf[j*8+2] * bflo(kx.y); a += qf[j*8+3] * bfhi(kx.y);
            a += qf[j*8+4] * bflo(kx.z); a += qf[j*8+5] * bfhi(kx.z);
            a += qf[j*8+6] * bflo(kx.w); a += qf[j*8+7] * bfhi(kx.w);
        }
        lg[e] = a;
    }

    // ---- exp-shift, sim reweight; defer 1/sum to output scale -----------
    float mx = lg[0];
#pragma unroll
    for (int e = 1; e < KK; e++) mx = fmaxf(mx, lg[e]);
    float sum = 0.f;
#pragma unroll
    for (int e = 0; e < KK; e++) {
        float p = __expf(lg[e] - mx) * sw_[e];
        sum += p;
        lg[e] = p;
    }
    const float inv = 1.0f / (1e-10f + sum);

    __syncthreads();   // all QK LDS reads done before V overwrite

    // ---- phase 2: stage V halo ------------------------------------------
    const ushort_t* vg = v + tpix * 256 + head * HD;
#pragma unroll 1
    for (int i = tid; i < 3200; i += 256) {
        int p = i >> 3, ch = i & 7;
        int rr = (p * 13108) >> 18;
        int cc = p - rr * 20;
        int h2 = min(max(th + rr - 2, 0), H_ - 1);
        int w2 = min(max(tw + cc - 2, 0), W_ - 1);
        const ushort_t* src = vg + (((size_t)((h2 << 8) + w2)) << 8) + ch * 8;
        *(uint4*)(kv + p * 72 + ch * 8) = *(const uint4*)src;
    }
    __syncthreads();

    // ---- PV (all 64 channels in registers) ------------------------------
    float oa[HD];
#pragma unroll
    for (int i = 0; i < HD; i++) oa[i] = 0.f;
#pragma unroll
    for (int e = 0; e < KK; e++) {
        const int di = e / 5 - 2, dj = e % 5 - 2;
        const int doff = di * 20 + dj;
        const ushort_t* vp = kb + (doff + 42) * 72;
        float wgt = lg[e];
#pragma unroll
        for (int j = 0; j < 8; j++) {
            uint4 vx = *(const uint4*)(vp + j * 8);
            oa[j*8+0] += wgt * bflo(vx.x); oa[j*8+1] += wgt * bfhi(vx.x);
            oa[j*8+2] += wgt * bflo(vx.y); oa[j*8+3] += wgt * bfhi(vx.y);
            oa[j*8+4] += wgt * bflo(vx.z); oa[j*8+5] += wgt * bfhi(vx.z);
            oa[j*8+6] += wgt * bflo(vx.w); oa[j*8+7] += wgt * bfhi(vx.w);
        }
    }

    // ---- scale, pack, store: ALL 64 channels (32 u32 = 8 uint4) ---------
    ushort_t* ab = ao + qpix * 256 + head * HD;
    unsigned pk[32];
#pragma unroll
    for (int j = 0; j < 32; j++)
        pk[j] = (unsigned)f2bf(oa[2*j] * inv)
              | ((unsigned)f2bf(oa[2*j+1] * inv) << 16);
    uint4* stp = (uint4*)ab;
#pragma unroll
    for (int i = 0; i < 8; i++)
        stp[i] = make_uint4(pk[i*4+0], pk[i*4+1], pk[i*4+2], pk[i*4+3]);
}

// ---------------------------------------------------------------------------
extern "C" void kernel_launch(void* const* d_in, const int* in_sizes, int n_in,
                              void* d_out, int out_size, void* d_ws, size_t ws_size,
                              hipStream_t stream)
{
    const float* x    = (const float*)d_in[0];
    const float* sims = (const float*)d_in[1];
    // d_in[2] = flows: zeros (wt = 0) -> unused
    const float* Wq   = (const float*)d_in[3];
    const float* Wk   = (const float*)d_in[4];
    const float* Wv   = (const float*)d_in[5];
    const float* Wp   = (const float*)d_in[6];
    float* out = (float*)d_out;

    const size_t NCH = (size_t)NPIX_ * 256;

    ushort_t* Wt = (ushort_t*)d_ws;                       // 512 KB
    ushort_t* Xt = (ushort_t*)((char*)d_ws + (1 << 20));
    ushort_t* qq = Xt + NCH;
    ushort_t* kk = qq + NCH;
    ushort_t* vv = kk + NCH;
    ushort_t* ao = vv + NCH;

    prep_w<<<1024, 256, 0, stream>>>(Wq, Wk, Wv, Wp, Wt);
    cast_x<<<dim3(HW_ / 64, C_ / 64, T_), 256, 0, stream>>>(x, Xt);

    // QKV: N = 768 (q|k|v stacked in Wt rows 0..767), pixel-major bf16 out
    gemm_mfma<<<dim3(NPIX_ / 128, 6), 256, 0, stream>>>(Xt, Wt, qq, kk, vv, nullptr, 0);

    attn_tile<<<dim3(W_ / 16, H_ / 16, T_ * NH), 256, 0, stream>>>(qq, kk, vv, sims, ao);

    // output projection: Wp^T at rows 768.., fp32 channel-major out
    gemm_mfma<<<dim3(NPIX_ / 128, 2), 256, 0, stream>>>(ao, Wt + 768 * 256,
                                                        nullptr, nullptr, nullptr, out, 1);
}

// Round 4
// 2225.117 us; speedup vs baseline: 1.8910x; 1.0566x over previous
//
#include <hip/hip_runtime.h>

#define T_  4
#define C_  256
#define H_  256
#define W_  256
#define S_  9
#define HW_ (H_*W_)
#define NH  4
#define HD  64
#define KK  25
#define NPIX_ (T_*HW_)

typedef unsigned short ushort_t;
typedef __bf16 bf16x8 __attribute__((ext_vector_type(8)));
typedef float  f32x4  __attribute__((ext_vector_type(4)));

__device__ __forceinline__ unsigned short f2bf(float f) {
    unsigned u = __builtin_bit_cast(unsigned, f);
    u += 0x7fffu + ((u >> 16) & 1u);          // RNE
    return (unsigned short)(u >> 16);
}
__device__ __forceinline__ float bflo(unsigned u) {
    return __builtin_bit_cast(float, u << 16);
}
__device__ __forceinline__ float bfhi(unsigned u) {
    return __builtin_bit_cast(float, u & 0xffff0000u);
}
__device__ __forceinline__ void gload16(const ushort_t* g, ushort_t* l) {
    __builtin_amdgcn_global_load_lds(
        (const __attribute__((address_space(1))) void*)g,
        (__attribute__((address_space(3))) void*)l, 16, 0, 0);
}

// ---------------------------------------------------------------------------
// Weight prep: Wt[1024][256] bf16; rows 0..255 = Wq^T * 0.125, 256.. = Wk^T,
// 512.. = Wv^T, 768.. = Wp^T.
// ---------------------------------------------------------------------------
__global__ __launch_bounds__(256)
void prep_w(const float* __restrict__ Wq, const float* __restrict__ Wk,
            const float* __restrict__ Wv, const float* __restrict__ Wp,
            ushort_t* __restrict__ Wt)
{
    int r = blockIdx.x;            // 0..1023
    int m = r >> 8, co = r & 255;
    int ci = threadIdx.x;
    const float* W = (m == 0) ? Wq : ((m == 1) ? Wk : ((m == 2) ? Wv : Wp));
    float s = (m == 0) ? 0.125f : 1.0f;
    Wt[(size_t)r * 256 + ci] = f2bf(W[(size_t)ci * 256 + co] * s);
}

// ---------------------------------------------------------------------------
// X cast+transpose: [T,C,HW] fp32 -> [T,HW,C] bf16.  64x64 LDS tiles.
// ---------------------------------------------------------------------------
__global__ __launch_bounds__(256)
void cast_x(const float* __restrict__ X, ushort_t* __restrict__ Xt)
{
    int hw0 = blockIdx.x * 64, c0 = blockIdx.y * 64, t = blockIdx.z;
    __shared__ ushort_t lds[64][68];
    int tid = threadIdx.x;
    const float* xb = X + ((size_t)t * C_ + c0) * HW_ + hw0;
#pragma unroll
    for (int i = 0; i < 4; i++) {
        int idx = tid + i * 256;
        int c = idx >> 4, col4 = idx & 15;
        float4 v = *(const float4*)(xb + (size_t)c * HW_ + col4 * 4);
        ushort4 u = make_ushort4(f2bf(v.x), f2bf(v.y), f2bf(v.z), f2bf(v.w));
        *(ushort4*)&lds[c][col4 * 4] = u;
    }
    __syncthreads();
    ushort_t* ob = Xt + ((size_t)t * HW_ + hw0) * C_ + c0;
#pragma unroll
    for (int i = 0; i < 4; i++) {
        int idx = tid + i * 256;
        int hw = idx >> 4, c4 = idx & 15;
        ushort4 u = make_ushort4(lds[c4 * 4 + 0][hw], lds[c4 * 4 + 1][hw],
                                 lds[c4 * 4 + 2][hw], lds[c4 * 4 + 3][hw]);
        *(ushort4*)(ob + (size_t)hw * C_ + c4 * 4) = u;
    }
}

// ---------------------------------------------------------------------------
// MFMA GEMM: C[n][co] = sum_ci A[n][ci] * Bt[co][ci].  Tile 128x128, BK=32.
// mode 0: bf16 out pixel-major [n][256], split by co into o0/o1/o2.
// mode 1: fp32 out channel-major [T,C,H,W] (float4 along n).
// ---------------------------------------------------------------------------
__global__ __launch_bounds__(256)
void gemm_mfma(const ushort_t* __restrict__ A, const ushort_t* __restrict__ Bt,
               ushort_t* __restrict__ o0, ushort_t* __restrict__ o1,
               ushort_t* __restrict__ o2, float* __restrict__ of, int mode)
{
    __shared__ ushort_t As[128 * 32];
    __shared__ ushort_t Bs[128 * 32];
    const int tid = threadIdx.x, ln = tid & 63, wv = tid >> 6;
    const int n0  = blockIdx.x * 128;
    const int co0 = blockIdx.y * 128;
    const int m_off = (wv & 1) * 64, n_off = (wv >> 1) * 64;

    f32x4 acc[4][4];
#pragma unroll
    for (int i = 0; i < 4; i++)
#pragma unroll
        for (int j = 0; j < 4; j++) acc[i][j] = (f32x4){0.f, 0.f, 0.f, 0.f};

    const int srow = ln >> 2, scol = (ln & 3) * 8;
    const ushort_t* gA = A  + (size_t)(n0  + srow) * 256 + scol;
    const ushort_t* gB = Bt + (size_t)(co0 + srow) * 256 + scol;
    const int quad = ln >> 4, lm = ln & 15;

#pragma unroll
    for (int k0 = 0; k0 < 256; k0 += 32) {
#pragma unroll
        for (int c = 0; c < 2; c++) {
            int rr = wv * 32 + c * 16;
            gload16(gA + (size_t)rr * 256 + k0, As + rr * 32);
            gload16(gB + (size_t)rr * 256 + k0, Bs + rr * 32);
        }
        __syncthreads();
        bf16x8 af[4], bfr[4];
#pragma unroll
        for (int mt = 0; mt < 4; mt++)
            af[mt] = *(const bf16x8*)&As[(m_off + mt * 16 + lm) * 32 + quad * 8];
#pragma unroll
        for (int nt = 0; nt < 4; nt++)
            bfr[nt] = *(const bf16x8*)&Bs[(n_off + nt * 16 + lm) * 32 + quad * 8];
#pragma unroll
        for (int mt = 0; mt < 4; mt++)
#pragma unroll
            for (int nt = 0; nt < 4; nt++)
                acc[mt][nt] = __builtin_amdgcn_mfma_f32_16x16x32_bf16(
                    af[mt], bfr[nt], acc[mt][nt], 0, 0, 0);
        __syncthreads();
    }

    if (mode == 0) {
        int arr = co0 >> 8;
        ushort_t* op = (arr == 0) ? o0 : ((arr == 1) ? o1 : o2);
        int cobase = (co0 & 255) + n_off;
#pragma unroll
        for (int mt = 0; mt < 4; mt++) {
            int nb = n0 + m_off + mt * 16 + quad * 4;
#pragma unroll
            for (int nt = 0; nt < 4; nt++) {
                int ci = cobase + nt * 16 + lm;
#pragma unroll
                for (int r = 0; r < 4; r++)
                    op[(size_t)(nb + r) * 256 + ci] = f2bf(acc[mt][nt][r]);
            }
        }
    } else {
#pragma unroll
        for (int mt = 0; mt < 4; mt++) {
            int nb = n0 + m_off + mt * 16 + quad * 4;
            int tt = nb >> 16, hwb = nb & (HW_ - 1);
            float* ob = of + (size_t)tt * (C_ * (size_t)HW_) + hwb;
#pragma unroll
            for (int nt = 0; nt < 4; nt++) {
                int cg = co0 + n_off + nt * 16 + lm;
                float4 val = make_float4(acc[mt][nt][0], acc[mt][nt][1],
                                         acc[mt][nt][2], acc[mt][nt][3]);
                *(float4*)(ob + (size_t)cg * HW_) = val;
            }
        }
    }
}

// ---------------------------------------------------------------------------
// Attention v6: LDS-tiled neighborhood attention, channel-chunked to avoid
// register spill (v5 had 256 VGPR + 2.3 GB scratch traffic).
// Block = (t, head, 16x16 pixel tile), 256 threads, 1 pixel/thread.
// K then V staged in LDS as 20x20 halo, 144 B/pixel (16B-aligned, stride
// 144 ≡ 16 mod 128 so consecutive halo pixels hit consecutive 16B slots).
// q stays PACKED (8 x uint4 = 32 VGPR); QK and PV iterate channel chunks
// of 8 with e=0..24 inner; only lg[25] persists across chunks.
// ---------------------------------------------------------------------------
__global__ __launch_bounds__(256)
void attn_tile(const ushort_t* __restrict__ q, const ushort_t* __restrict__ k,
               const ushort_t* __restrict__ v, const float* __restrict__ sims,
               ushort_t* __restrict__ ao)
{
    const int tw = blockIdx.x * 16, th = blockIdx.y * 16;
    const int t = blockIdx.z >> 2, head = blockIdx.z & 3;
    const int tid = threadIdx.x;
    const int r = tid >> 4, c = tid & 15;

    __shared__ float4 smem4[3600];            // 57600 B
    ushort_t* kv = (ushort_t*)smem4;          // [400] x 72 ushorts (144 B)
    float*    sm = (float*)smem4;             // [400] x 12 floats

    const size_t tpix = (size_t)t * HW_;
    const int p0 = (r + 2) * 20 + (c + 2);    // own pixel in halo coords

    // ---- q into registers, PACKED (8 uint4 = 32 VGPR) -------------------
    const size_t qpix = tpix + (size_t)((th + r) << 8) + (tw + c);
    const ushort_t* qb = q + qpix * 256 + head * HD;
    uint4 qp0 = *(const uint4*)(qb +  0), qp1 = *(const uint4*)(qb +  8);
    uint4 qp2 = *(const uint4*)(qb + 16), qp3 = *(const uint4*)(qb + 24);
    uint4 qp4 = *(const uint4*)(qb + 32), qp5 = *(const uint4*)(qb + 40);
    uint4 qp6 = *(const uint4*)(qb + 48), qp7 = *(const uint4*)(qb + 56);

    // ---- phase 0: stage sims halo [400][12] -----------------------------
#pragma unroll 1
    for (int i = tid; i < 3600; i += 256) {
        int p = (i * 7282) >> 16;             // i / 9  (valid for i < 32768)
        int s = i - p * 9;
        int rr = (p * 13108) >> 18;           // p / 20 (valid for p < 819)
        int cc = p - rr * 20;
        int h2 = min(max(th + rr - 2, 0), H_ - 1);
        int w2 = min(max(tw + cc - 2, 0), W_ - 1);
        sm[p * 12 + s] = sims[(((size_t)t * S_ + s) << 16) + (h2 << 8) + w2];
    }
    __syncthreads();

    // ---- sw[25] = superpixel similarity weights (registers) -------------
    float sw_[KK];
    {
        const float* so = sm + p0 * 12;
        float4 A = *(const float4*)so;
        float4 B = *(const float4*)(so + 4);
        float  C = so[8];
        const float* sb = sm + (p0 - 42) * 12;
#pragma unroll
        for (int e = 0; e < KK; e++) {
            const int di = e / 5 - 2, dj = e % 5 - 2;
            const int doff = di * 20 + dj;
            const float* sn = sb + (doff + 42) * 12;
            float4 X = *(const float4*)sn;
            float4 Y = *(const float4*)(sn + 4);
            float  Z = sn[8];
            sw_[e] = A.x*X.x + A.y*X.y + A.z*X.z + A.w*X.w
                   + B.x*Y.x + B.y*Y.y + B.z*Y.z + B.w*Y.w + C*Z;
        }
    }
    __syncthreads();

    // ---- phase 1: stage K halo (400 px x 64 ch, 144 B/px) ---------------
    const ushort_t* kg = k + tpix * 256 + head * HD;
#pragma unroll 1
    for (int i = tid; i < 3200; i += 256) {
        int p = i >> 3, ch = i & 7;
        int rr = (p * 13108) >> 18;
        int cc = p - rr * 20;
        int h2 = min(max(th + rr - 2, 0), H_ - 1);
        int w2 = min(max(tw + cc - 2, 0), W_ - 1);
        const ushort_t* src = kg + (((size_t)((h2 << 8) + w2)) << 8) + ch * 8;
        *(uint4*)(kv + p * 72 + ch * 8) = *(const uint4*)src;
    }
    __syncthreads();

    // ---- QK logits: channel chunks of 8, e inner; only lg persists ------
    float lg[KK];
#pragma unroll
    for (int e = 0; e < KK; e++) lg[e] = 0.f;

    const ushort_t* kb = kv + (size_t)(p0 - 42) * 72;
#pragma unroll
    for (int j = 0; j < 8; j++) {
        uint4 qx = (j == 0) ? qp0 : (j == 1) ? qp1 : (j == 2) ? qp2 :
                   (j == 3) ? qp3 : (j == 4) ? qp4 : (j == 5) ? qp5 :
                   (j == 6) ? qp6 : qp7;               // j is compile-time
        float q0 = bflo(qx.x), q1 = bfhi(qx.x);
        float q2 = bflo(qx.y), q3 = bfhi(qx.y);
        float q4 = bflo(qx.z), q5 = bfhi(qx.z);
        float q6 = bflo(qx.w), q7 = bfhi(qx.w);
#pragma unroll
        for (int e = 0; e < KK; e++) {
            const int di = e / 5 - 2, dj = e % 5 - 2;
            const int doff = di * 20 + dj;
            uint4 kx = *(const uint4*)(kb + (doff + 42) * 72 + j * 8);
            float a = lg[e];
            a += q0 * bflo(kx.x); a += q1 * bfhi(kx.x);
            a += q2 * bflo(kx.y); a += q3 * bfhi(kx.y);
            a += q4 * bflo(kx.z); a += q5 * bfhi(kx.z);
            a += q6 * bflo(kx.w); a += q7 * bfhi(kx.w);
            lg[e] = a;
        }
    }

    // ---- exp-shift, sim reweight; fold 1/sum into lg --------------------
    float mx = lg[0];
#pragma unroll
    for (int e = 1; e < KK; e++) mx = fmaxf(mx, lg[e]);
    float sum = 0.f;
#pragma unroll
    for (int e = 0; e < KK; e++) {
        float p = __expf(lg[e] - mx) * sw_[e];
        sum += p;
        lg[e] = p;
    }
    const float inv = 1.0f / (1e-10f + sum);
#pragma unroll
    for (int e = 0; e < KK; e++) lg[e] *= inv;

    __syncthreads();   // all QK LDS reads done before V overwrite

    // ---- phase 2: stage V halo ------------------------------------------
    const ushort_t* vg = v + tpix * 256 + head * HD;
#pragma unroll 1
    for (int i = tid; i < 3200; i += 256) {
        int p = i >> 3, ch = i & 7;
        int rr = (p * 13108) >> 18;
        int cc = p - rr * 20;
        int h2 = min(max(th + rr - 2, 0), H_ - 1);
        int w2 = min(max(tw + cc - 2, 0), W_ - 1);
        const ushort_t* src = vg + (((size_t)((h2 << 8) + w2)) << 8) + ch * 8;
        *(uint4*)(kv + p * 72 + ch * 8) = *(const uint4*)src;
    }
    __syncthreads();

    // ---- PV: channel chunks of 8, store each chunk immediately ----------
    ushort_t* ab = ao + qpix * 256 + head * HD;
#pragma unroll
    for (int j = 0; j < 8; j++) {
        float o0 = 0.f, o1 = 0.f, o2 = 0.f, o3 = 0.f;
        float o4 = 0.f, o5 = 0.f, o6 = 0.f, o7 = 0.f;
#pragma unroll
        for (int e = 0; e < KK; e++) {
            const int di = e / 5 - 2, dj = e % 5 - 2;
            const int doff = di * 20 + dj;
            uint4 vx = *(const uint4*)(kb + (doff + 42) * 72 + j * 8);
            float wgt = lg[e];
            o0 += wgt * bflo(vx.x); o1 += wgt * bfhi(vx.x);
            o2 += wgt * bflo(vx.y); o3 += wgt * bfhi(vx.y);
            o4 += wgt * bflo(vx.z); o5 += wgt * bfhi(vx.z);
            o6 += wgt * bflo(vx.w); o7 += wgt * bfhi(vx.w);
        }
        uint4 st;
        st.x = (unsigned)f2bf(o0) | ((unsigned)f2bf(o1) << 16);
        st.y = (unsigned)f2bf(o2) | ((unsigned)f2bf(o3) << 16);
        st.z = (unsigned)f2bf(o4) | ((unsigned)f2bf(o5) << 16);
        st.w = (unsigned)f2bf(o6) | ((unsigned)f2bf(o7) << 16);
        *(uint4*)(ab + j * 8) = st;
    }
}

// ---------------------------------------------------------------------------
extern "C" void kernel_launch(void* const* d_in, const int* in_sizes, int n_in,
                              void* d_out, int out_size, void* d_ws, size_t ws_size,
                              hipStream_t stream)
{
    const float* x    = (const float*)d_in[0];
    const float* sims = (const float*)d_in[1];
    // d_in[2] = flows: zeros (wt = 0) -> unused
    const float* Wq   = (const float*)d_in[3];
    const float* Wk   = (const float*)d_in[4];
    const float* Wv   = (const float*)d_in[5];
    const float* Wp   = (const float*)d_in[6];
    float* out = (float*)d_out;

    const size_t NCH = (size_t)NPIX_ * 256;

    ushort_t* Wt = (ushort_t*)d_ws;                       // 512 KB
    ushort_t* Xt = (ushort_t*)((char*)d_ws + (1 << 20));
    ushort_t* qq = Xt + NCH;
    ushort_t* kk = qq + NCH;
    ushort_t* vv = kk + NCH;
    ushort_t* ao = vv + NCH;

    prep_w<<<1024, 256, 0, stream>>>(Wq, Wk, Wv, Wp, Wt);
    cast_x<<<dim3(HW_ / 64, C_ / 64, T_), 256, 0, stream>>>(x, Xt);

    // QKV: N = 768 (q|k|v stacked in Wt rows 0..767), pixel-major bf16 out
    gemm_mfma<<<dim3(NPIX_ / 128, 6), 256, 0, stream>>>(Xt, Wt, qq, kk, vv, nullptr, 0);

    attn_tile<<<dim3(W_ / 16, H_ / 16, T_ * NH), 256, 0, stream>>>(qq, kk, vv, sims, ao);

    // output projection: Wp^T at rows 768.., fp32 channel-major out
    gemm_mfma<<<dim3(NPIX_ / 128, 2), 256, 0, stream>>>(ao, Wt + 768 * 256,
                                                        nullptr, nullptr, nullptr, out, 1);
}